// Round 1
// baseline (753.132 us; speedup 1.0000x reference)
//
#include <hip/hip_runtime.h>

// TemporalCrossAttention — MI355X (gfx950)
// B=8192, T=16, QD=320, HEADS=8, DH=64, INNER=512. ROWS = 131072.
// Sparse causal mask == attend to {t-1, t} only; rel tables only at idx 15,16.

typedef __attribute__((ext_vector_type(8))) short short8;
typedef __attribute__((ext_vector_type(4))) float floatx4;

#define NWQKV (8*192*320)   // 491520 elems
#define NWO   (320*512)     // 163840 elems

__device__ __forceinline__ unsigned short f2b(float x) {
  union { float f; unsigned int u; } t; t.f = x;
  unsigned int r = t.u + 0x7FFFu + ((t.u >> 16) & 1u);
  return (unsigned short)(r >> 16);
}

// ---------------------------------------------------------------- prep ----
// wqkvT[h][c][k] (c: 0-63 q, 64-127 k, 128-191 v dims), woT[c][k] — bf16.
__global__ __launch_bounds__(256) void prep_kernel(
    const float* __restrict__ Wq, const float* __restrict__ Wk,
    const float* __restrict__ Wv, const float* __restrict__ Wo,
    unsigned short* __restrict__ wqkvT, unsigned short* __restrict__ woT) {
  int tid = blockIdx.x * 256 + threadIdx.x;
  if (tid < NWQKV) {
    int k = tid % 320;
    int c = (tid / 320) % 192;
    int h = tid / (320 * 192);
    int sel = c >> 6, d = c & 63;
    const float* W = (sel == 0) ? Wq : ((sel == 1) ? Wk : Wv);
    wqkvT[tid] = f2b(W[k * 512 + h * 64 + d]);
  } else {
    int i = tid - NWQKV;          // grid sized exactly: i < NWO
    int k = i & 511;
    int c = i >> 9;
    woT[i] = f2b(Wo[k * 320 + c]);
  }
}

// ------------------------------------------------- fused qkv + attention ----
// grid 1024 x 512 threads. Block = 128 rows. Wave = 16 rows = one batch elem.
// Per head: wave computes q|k|v (192 cols) as 12 16x16 frags, then 2-key
// softmax fully in-registers (16-lane shfl reduce), writes attnout bf16.
__global__ __launch_bounds__(512) void qkv_attn_kernel(
    const float* __restrict__ x, const float* __restrict__ relk,
    const float* __restrict__ relv, const unsigned short* __restrict__ wqkvT,
    unsigned short* __restrict__ attnout) {
  __shared__ unsigned short bsT[192][40];   // [col][k] padded 32->40: 2-way max
  const int tid = threadIdx.x;
  const int lane = tid & 63;
  const int wm = tid >> 6;          // wave 0..7
  const int lr = lane & 15;
  const int g = lane >> 4;          // 0..3
  const int wr0 = blockIdx.x * 128 + wm * 16;

  // rel vectors for this lane's dims d = f*16+lr
  float rk15v[4], rk16v[4], rv15v[4], rv16v[4];
#pragma unroll
  for (int f = 0; f < 4; f++) {
    int d = f * 16 + lr;
    rk15v[f] = relk[15 * 64 + d];
    rk16v[f] = relk[16 * 64 + d];
    rv15v[f] = relv[15 * 64 + d];
    rv16v[f] = relv[16 * 64 + d];
  }

  // A fragments in registers for all 10 K-steps (row = wr0+lr, k = ks*32+g*8)
  short8 af[10];
  const float* xrow = x + (size_t)(wr0 + lr) * 320;
#pragma unroll
  for (int ks = 0; ks < 10; ks++) {
    const float4 u0 = *(const float4*)(xrow + ks * 32 + g * 8);
    const float4 u1 = *(const float4*)(xrow + ks * 32 + g * 8 + 4);
    short8 a;
    a[0] = (short)f2b(u0.x); a[1] = (short)f2b(u0.y);
    a[2] = (short)f2b(u0.z); a[3] = (short)f2b(u0.w);
    a[4] = (short)f2b(u1.x); a[5] = (short)f2b(u1.y);
    a[6] = (short)f2b(u1.z); a[7] = (short)f2b(u1.w);
    af[ks] = a;
  }

  for (int h = 0; h < 8; h++) {
    floatx4 acc[12];
#pragma unroll
    for (int f = 0; f < 12; f++) acc[f] = (floatx4){0.f, 0.f, 0.f, 0.f};
    const unsigned short* wbase = wqkvT + h * (192 * 320);

    for (int ks = 0; ks < 10; ks++) {
      __syncthreads();                       // previous iter's reads done
      // stage B chunk: 192 cols x 32 k (768 slots of 16B)
#pragma unroll
      for (int s = 0; s < 2; s++) {
        int slot = tid + s * 512;
        if (slot < 768) {
          int c = slot >> 2, kc = slot & 3;
          *(short8*)(&bsT[c][kc * 8]) =
              *(const short8*)(wbase + c * 320 + ks * 32 + kc * 8);
        }
      }
      __syncthreads();
#pragma unroll
      for (int f = 0; f < 12; f++) {
        short8 b = *(const short8*)(&bsT[f * 16 + lr][g * 8]);
        acc[f] = __builtin_amdgcn_mfma_f32_16x16x32_bf16(af[ks], b, acc[f], 0, 0, 0);
      }
    }

    // ---- attention epilogue: rows t = g*4+reg, this lane holds dims f*16+lr
    float s0[4], s1[4];
#pragma unroll
    for (int reg = 0; reg < 4; reg++) {
      float pq = 0.f, pp = 0.f, p16 = 0.f, p15 = 0.f;
#pragma unroll
      for (int f = 0; f < 4; f++) {
        float q = acc[f][reg];
        float kk = acc[4 + f][reg];
        float kprev = (reg > 0) ? acc[4 + f][reg - 1]
                                : __shfl(acc[4 + f][3], (lane - 16) & 63, 64);
        pq  += q * kk;
        pp  += q * kprev;     // garbage for t==0 (group0,reg0) — weighted 0 later
        p16 += q * rk16v[f];
        p15 += q * rk15v[f];
      }
#pragma unroll
      for (int m = 1; m < 16; m <<= 1) {
        pq  += __shfl_xor(pq, m, 16);
        pp  += __shfl_xor(pp, m, 16);
        p16 += __shfl_xor(p16, m, 16);
        p15 += __shfl_xor(p15, m, 16);
      }
      s0[reg] = (pq + p16) * 0.125f;   // s = t   (rel idx 16)
      s1[reg] = (pp + p15) * 0.125f;   // s = t-1 (rel idx 15)
    }

#pragma unroll
    for (int reg = 0; reg < 4; reg++) {
      int t = g * 4 + reg;
      float S0 = s0[reg], S1 = s1[reg];
      float mm = fmaxf(S0, S1);
      float e0 = __expf(S0 - mm), e1 = __expf(S1 - mm);
      float inv = 1.f / (e0 + e1);
      float a0 = (t == 0) ? 1.f : e0 * inv;
      float a1 = (t == 0) ? 0.f : e1 * inv;
      size_t base = (size_t)(wr0 + t) * 512 + h * 64 + lr;
#pragma unroll
      for (int f = 0; f < 4; f++) {
        float vv = acc[8 + f][reg];
        float vp = (reg > 0) ? acc[8 + f][reg - 1]
                             : __shfl(acc[8 + f][3], (lane - 16) & 63, 64);
        float o = a0 * (vv + rv16v[f]) + a1 * (vp + rv15v[f]);
        attnout[base + f * 16] = f2b(o);
      }
    }
  }
}

// ------------------------------------------------------- output projection ----
// out[131072,320] = attnout[131072,512]@Wo + bo, bf16 MFMA, f32 out.
__global__ __launch_bounds__(512) void out_proj_kernel(
    const unsigned short* __restrict__ attnout,
    const unsigned short* __restrict__ woT,
    const float* __restrict__ bo, float* __restrict__ out) {
  __shared__ unsigned short bsT[320][40];
  const int tid = threadIdx.x;
  const int lane = tid & 63;
  const int wm = tid >> 6;
  const int lr = lane & 15;
  const int g = lane >> 4;
  const int wr0 = blockIdx.x * 128 + wm * 16;

  short8 af[16];
  const unsigned short* arow = attnout + (size_t)(wr0 + lr) * 512;
#pragma unroll
  for (int ks = 0; ks < 16; ks++)
    af[ks] = *(const short8*)(arow + ks * 32 + g * 8);

  floatx4 acc[20];
#pragma unroll
  for (int f = 0; f < 20; f++) acc[f] = (floatx4){0.f, 0.f, 0.f, 0.f};

  for (int ks = 0; ks < 16; ks++) {
    __syncthreads();
#pragma unroll
    for (int s = 0; s < 3; s++) {
      int slot = tid + s * 512;
      if (slot < 1280) {
        int c = slot >> 2, kc = slot & 3;
        *(short8*)(&bsT[c][kc * 8]) =
            *(const short8*)(woT + c * 512 + ks * 32 + kc * 8);
      }
    }
    __syncthreads();
#pragma unroll
    for (int f = 0; f < 20; f++) {
      short8 b = *(const short8*)(&bsT[f * 16 + lr][g * 8]);
      acc[f] = __builtin_amdgcn_mfma_f32_16x16x32_bf16(af[ks], b, acc[f], 0, 0, 0);
    }
  }

#pragma unroll
  for (int reg = 0; reg < 4; reg++) {
    float* orow = out + (size_t)(wr0 + g * 4 + reg) * 320;
#pragma unroll
    for (int f = 0; f < 20; f++)
      orow[f * 16 + lr] = acc[f][reg] + bo[f * 16 + lr];
  }
}

// ---------------------------------------------------------------- launch ----
extern "C" void kernel_launch(void* const* d_in, const int* in_sizes, int n_in,
                              void* d_out, int out_size, void* d_ws, size_t ws_size,
                              hipStream_t stream) {
  (void)in_sizes; (void)n_in; (void)out_size; (void)ws_size;
  const float* x    = (const float*)d_in[0];
  const float* Wq   = (const float*)d_in[1];
  const float* Wk   = (const float*)d_in[2];
  const float* Wv   = (const float*)d_in[3];
  const float* Wo   = (const float*)d_in[4];
  const float* bo   = (const float*)d_in[5];
  const float* relk = (const float*)d_in[6];
  const float* relv = (const float*)d_in[7];
  float* out = (float*)d_out;

  unsigned short* wqkvT   = (unsigned short*)d_ws;              // 983040 B
  unsigned short* woT     = wqkvT + NWQKV;                      // 327680 B
  unsigned short* attnout = woT + NWO;                          // 134217728 B
  // total ws use: 135,528,448 B

  prep_kernel<<<(NWQKV + NWO) / 256, 256, 0, stream>>>(Wq, Wk, Wv, Wo, wqkvT, woT);
  qkv_attn_kernel<<<1024, 512, 0, stream>>>(x, relk, relv, wqkvT, attnout);
  out_proj_kernel<<<1024, 512, 0, stream>>>(attnout, woT, bo, out);
}

// Round 2
// 529.138 us; speedup vs baseline: 1.4233x; 1.4233x over previous
//
#include <hip/hip_runtime.h>

// TemporalCrossAttention — MI355X (gfx950)
// B=8192, T=16, QD=320, HEADS=8, DH=64, INNER=512. ROWS = 131072.
// Mask == attend to {t-1, t}; rel tables only at idx 15,16.

typedef __attribute__((ext_vector_type(8))) short short8;
typedef __attribute__((ext_vector_type(4))) float floatx4;

#define NWQKV (8*192*320)   // 491520 elems
#define NWO   (320*512)     // 163840 elems

__device__ __forceinline__ unsigned short f2b(float x) {
  union { float f; unsigned int u; } t; t.f = x;
  unsigned int r = t.u + 0x7FFFu + ((t.u >> 16) & 1u);
  return (unsigned short)(r >> 16);
}

typedef const __attribute__((address_space(1))) unsigned int* gas_ptr;
typedef __attribute__((address_space(3))) unsigned int* las_ptr;

// 16B async global->LDS. lds ptr must be wave-uniform; HW scatters lane i to
// base + i*16 (m104). Global src is per-lane.
__device__ __forceinline__ void gload16(const void* g, void* l) {
  __builtin_amdgcn_global_load_lds((gas_ptr)g, (las_ptr)l, 16, 0, 0);
}

// ---------------------------------------------------------------- prep ----
// wqkvT[h][c][k] (c: 0-63 q, 64-127 k, 128-191 v dims), woT[c][k] — bf16.
__global__ __launch_bounds__(256) void prep_kernel(
    const float* __restrict__ Wq, const float* __restrict__ Wk,
    const float* __restrict__ Wv, const float* __restrict__ Wo,
    unsigned short* __restrict__ wqkvT, unsigned short* __restrict__ woT) {
  int tid = blockIdx.x * 256 + threadIdx.x;
  if (tid < NWQKV) {
    int k = tid % 320;
    int c = (tid / 320) % 192;
    int h = tid / (320 * 192);
    int sel = c >> 6, d = c & 63;
    const float* W = (sel == 0) ? Wq : ((sel == 1) ? Wk : Wv);
    wqkvT[tid] = f2b(W[k * 512 + h * 64 + d]);
  } else {
    int i = tid - NWQKV;          // grid sized exactly: i < NWO
    int k = i & 511;
    int c = i >> 9;
    woT[i] = f2b(Wo[k * 320 + c]);
  }
}

// ------------------------------------------------- fused qkv + attention ----
// grid 512 x 512 threads. Block = 256 rows. Wave = 32 rows (2 batch elems).
// A (x rows, bf16) resident in regs for all K; B double-buffered in LDS via
// global_load_lds, fragment-ordered (conflict-free), 1 barrier per K32-step.
__global__ __launch_bounds__(512, 2) void qkv_attn_kernel(
    const float* __restrict__ x, const float* __restrict__ relk,
    const float* __restrict__ relv, const unsigned short* __restrict__ wqkvT,
    unsigned short* __restrict__ attnout) {
  __shared__ short8 bq[2][768];         // 12 frags x 64 lanes x 16B, x2 buf
  const int tid = threadIdx.x;
  const int lane = tid & 63;
  const int w = tid >> 6;               // wave 0..7
  const int lr = lane & 15;
  const int g = lane >> 4;              // 0..3
  const int wr0 = blockIdx.x * 256 + w * 32;

  float rk15v[4], rk16v[4], rv15v[4], rv16v[4];
#pragma unroll
  for (int f = 0; f < 4; f++) {
    int d = f * 16 + lr;
    rk15v[f] = relk[15 * 64 + d];
    rk16v[f] = relk[16 * 64 + d];
    rv15v[f] = relv[15 * 64 + d];
    rv16v[f] = relv[16 * 64 + d];
  }

  // A fragments: row = wr0 + r*16 + lr, k = ks*32 + g*8
  short8 af[2][10];
#pragma unroll
  for (int r = 0; r < 2; r++) {
    const float* xrow = x + (size_t)(wr0 + r * 16 + lr) * 320;
#pragma unroll
    for (int ks = 0; ks < 10; ks++) {
      const float4 u0 = *(const float4*)(xrow + ks * 32 + g * 8);
      const float4 u1 = *(const float4*)(xrow + ks * 32 + g * 8 + 4);
      short8 a;
      a[0] = (short)f2b(u0.x); a[1] = (short)f2b(u0.y);
      a[2] = (short)f2b(u0.z); a[3] = (short)f2b(u0.w);
      a[4] = (short)f2b(u1.x); a[5] = (short)f2b(u1.y);
      a[6] = (short)f2b(u1.z); a[7] = (short)f2b(u1.w);
      af[r][ks] = a;
    }
  }

  floatx4 acc[2][12];
#pragma unroll
  for (int r = 0; r < 2; r++)
#pragma unroll
    for (int f = 0; f < 12; f++) acc[r][f] = (floatx4){0.f, 0.f, 0.f, 0.f};

  // stage weights for (h,ks) into buffer cb. Wave w stages frag nf=w (+8+w).
  auto stage = [&](int h, int ks, int cb) {
    const unsigned short* wb = wqkvT + h * 61440 + ks * 32;
    {
      int nf = w;
      gload16(wb + (nf * 16 + lr) * 320 + g * 8, &bq[cb][nf * 64]);
    }
    if (w < 4) {
      int nf = 8 + w;
      gload16(wb + (nf * 16 + lr) * 320 + g * 8, &bq[cb][nf * 64]);
    }
  };

  stage(0, 0, 0);
  for (int h = 0; h < 8; ++h) {
#pragma unroll
    for (int ksi = 0; ksi < 10; ++ksi) {
      const int cb = ksi & 1;           // (h*10+ksi)&1 == ksi&1
      __syncthreads();                  // drains stage(S) + prev reads
      if (h * 10 + ksi < 79) {          // issue stage(S+1) under compute(S)
        int ksn = (ksi == 9) ? 0 : ksi + 1;
        int hn = (ksi == 9) ? h + 1 : h;
        stage(hn, ksn, cb ^ 1);
      }
#pragma unroll
      for (int nf = 0; nf < 12; ++nf) {
        short8 b = bq[cb][nf * 64 + lane];
        acc[0][nf] = __builtin_amdgcn_mfma_f32_16x16x32_bf16(af[0][ksi], b, acc[0][nf], 0, 0, 0);
        acc[1][nf] = __builtin_amdgcn_mfma_f32_16x16x32_bf16(af[1][ksi], b, acc[1][nf], 0, 0, 0);
      }
    }

    // ---- attention epilogue per rowset (one batch elem each); regs only,
    // overlaps the already-issued stage(h+1,0) loads.
#pragma unroll
    for (int r = 0; r < 2; ++r) {
      float s0[4], s1[4];
#pragma unroll
      for (int reg = 0; reg < 4; ++reg) {
        float c0 = 0.f, c1 = 0.f;
#pragma unroll
        for (int f = 0; f < 4; ++f) {
          float q = acc[r][f][reg];
          float kk = acc[r][4 + f][reg];
          float kp = (reg > 0) ? acc[r][4 + f][reg - 1]
                               : __shfl(acc[r][4 + f][3], (lane - 16) & 63, 64);
          c0 += q * (kk + rk16v[f]);
          c1 += q * (kp + rk15v[f]);
        }
#pragma unroll
        for (int m = 1; m < 16; m <<= 1) {
          c0 += __shfl_xor(c0, m, 16);
          c1 += __shfl_xor(c1, m, 16);
        }
        s0[reg] = c0 * 0.125f;
        s1[reg] = c1 * 0.125f;
      }
#pragma unroll
      for (int reg = 0; reg < 4; ++reg) {
        int t = g * 4 + reg;
        float S0 = s0[reg], S1 = s1[reg];
        float mm = fmaxf(S0, S1);
        float e0 = __expf(S0 - mm), e1 = __expf(S1 - mm);
        float inv = 1.f / (e0 + e1);
        float a0 = (t == 0) ? 1.f : e0 * inv;
        float a1 = (t == 0) ? 0.f : e1 * inv;
        size_t base = (size_t)(wr0 + r * 16 + t) * 512 + h * 64 + lr;
#pragma unroll
        for (int f = 0; f < 4; ++f) {
          float vv = acc[r][8 + f][reg];
          float vp = (reg > 0) ? acc[r][8 + f][reg - 1]
                               : __shfl(acc[r][8 + f][3], (lane - 16) & 63, 64);
          attnout[base + f * 16] = f2b(a0 * (vv + rv16v[f]) + a1 * (vp + rv15v[f]));
        }
      }
    }
#pragma unroll
    for (int r = 0; r < 2; ++r)
#pragma unroll
      for (int f = 0; f < 12; ++f) acc[r][f] = (floatx4){0.f, 0.f, 0.f, 0.f};
  }
}

// ------------------------------------------------------- output projection ----
// out[131072,320] = attnout@Wo + bo. Block = 128 rows x 320 cols, 8 waves:
// wave (rg=w>>1, half=w&1) does rows rg*32..+31, cols half*160..+159.
// A and B both staged via global_load_lds double-buffer, frag-ordered LDS.
__global__ __launch_bounds__(512, 4) void out_proj_kernel(
    const unsigned short* __restrict__ attnout,
    const unsigned short* __restrict__ woT,
    const float* __restrict__ bo, float* __restrict__ out) {
  __shared__ short8 sB[2][1280];        // 20 frags x 64 x 16B, x2
  __shared__ short8 sA[2][512];         // 8 rowset-frags x 64 x 16B, x2
  const int tid = threadIdx.x;
  const int lane = tid & 63;
  const int w = tid >> 6;
  const int lr = lane & 15;
  const int g = lane >> 4;
  const int rg = w >> 1, half = w & 1;
  const int rowbase = blockIdx.x * 128;

  auto stage = [&](int s, int cb) {
    const int ko = s * 32 + g * 8;
    { int c = w;      gload16(woT + (c * 16 + lr) * 512 + ko, &sB[cb][c * 64]); }
    { int c = 8 + w;  gload16(woT + (c * 16 + lr) * 512 + ko, &sB[cb][c * 64]); }
    if (w < 4) { int c = 16 + w;
                 gload16(woT + (c * 16 + lr) * 512 + ko, &sB[cb][c * 64]); }
    gload16(attnout + (size_t)(rowbase + w * 16 + lr) * 512 + ko, &sA[cb][w * 64]);
  };

  floatx4 acc[2][10];
#pragma unroll
  for (int r = 0; r < 2; r++)
#pragma unroll
    for (int f = 0; f < 10; f++) acc[r][f] = (floatx4){0.f, 0.f, 0.f, 0.f};

  stage(0, 0);
  for (int kt = 0; kt < 8; ++kt) {
#pragma unroll
    for (int ph = 0; ph < 2; ++ph) {
      const int cb = ph;
      const int s = kt * 2 + ph;
      __syncthreads();
      if (s < 15) stage(s + 1, cb ^ 1);
      short8 a0 = sA[cb][(rg * 2 + 0) * 64 + lane];
      short8 a1 = sA[cb][(rg * 2 + 1) * 64 + lane];
#pragma unroll
      for (int nf = 0; nf < 10; ++nf) {
        short8 b = sB[cb][(half * 10 + nf) * 64 + lane];
        acc[0][nf] = __builtin_amdgcn_mfma_f32_16x16x32_bf16(a0, b, acc[0][nf], 0, 0, 0);
        acc[1][nf] = __builtin_amdgcn_mfma_f32_16x16x32_bf16(a1, b, acc[1][nf], 0, 0, 0);
      }
    }
  }

#pragma unroll
  for (int r = 0; r < 2; ++r)
#pragma unroll
    for (int nf = 0; nf < 10; ++nf) {
      int col = half * 160 + nf * 16 + lr;
      float bb = bo[col];
#pragma unroll
      for (int reg = 0; reg < 4; ++reg) {
        int row = rowbase + rg * 32 + r * 16 + g * 4 + reg;
        out[(size_t)row * 320 + col] = acc[r][nf][reg] + bb;
      }
    }
}

// ---------------------------------------------------------------- launch ----
extern "C" void kernel_launch(void* const* d_in, const int* in_sizes, int n_in,
                              void* d_out, int out_size, void* d_ws, size_t ws_size,
                              hipStream_t stream) {
  (void)in_sizes; (void)n_in; (void)out_size; (void)ws_size;
  const float* x    = (const float*)d_in[0];
  const float* Wq   = (const float*)d_in[1];
  const float* Wk   = (const float*)d_in[2];
  const float* Wv   = (const float*)d_in[3];
  const float* Wo   = (const float*)d_in[4];
  const float* bo   = (const float*)d_in[5];
  const float* relk = (const float*)d_in[6];
  const float* relv = (const float*)d_in[7];
  float* out = (float*)d_out;

  unsigned short* wqkvT   = (unsigned short*)d_ws;              // 983040 B
  unsigned short* woT     = wqkvT + NWQKV;                      // 327680 B
  unsigned short* attnout = woT + NWO;                          // 134217728 B

  prep_kernel<<<(NWQKV + NWO) / 256, 256, 0, stream>>>(Wq, Wk, Wv, Wo, wqkvT, woT);
  qkv_attn_kernel<<<512, 512, 0, stream>>>(x, relk, relv, wqkvT, attnout);
  out_proj_kernel<<<1024, 512, 0, stream>>>(attnout, woT, bo, out);
}